// Round 6
// baseline (111.286 us; speedup 1.0000x reference)
//
#include <hip/hip_runtime.h>

// out[b,n] = sum_m exp(-||qp[b,n,:2]-sp[b,m,:2]||) * f[b,m] / sum_m exp(-...)
// Shapes: qp [4,4096,3], sp [4,8192,3], feats [4,8192,1], out [4,4096,1] fp32.
//
// R15: pk-f32 inline asm is DEAD (4 failed encodings across 2 sessions, R12/
// R14 both wrong with different values -> unverifiable blind; do not retry).
// New lever: the trans ops themselves. w = exp2(-sqrt(t)) is 1-D in
// t=(log2e*d)^2; test threshold is 1.0e-3 (60x headroom over R13's 1.5e-5).
// Replace sqrt+exp with piecewise-linear table over t's float bits (log-scale
// beats the sqrt singularity): 64 seg/octave x 32 octaves (t in [2^-24,2^8],
// clamped; clamp-below err<=1.7e-4 self-cancelling, interp err ~2.5e-5).
// Entry = (b,c), w = fma(b,t,c). Split b/c arrays -> 2 ds_read_b32/point,
// ~2-way random bank spread (free per m136). Table built per block (8
// entries/thread, ~3% of loop). LDS 18KB -> 4 blocks/CU unchanged.
// Model: body 94 -> ~60-75 cyc (-64 trans, +20 int/lookup, +~24 LDS).
// Predict main 40->28-33us, total ~75-80us, absmax ~1e-4 (PASS w/ margin).

#define B_DIM   4
#define N_DIM   4096
#define M_DIM   8192
#define NQ      (B_DIM * N_DIM)     // 16384
#define THREADS 256
#define QPT     4                   // queries per thread
#define QPB     (THREADS * QPT)     // 1024 queries per block
#define QGROUPS (NQ / QPB)          // 16
#define SPLITS  64                  // M splits (blockIdx.y) -> 1024 blocks
#define CHUNK   (M_DIM / SPLITS)    // 128 scene points per block
#define PAIRS   (CHUNK / 2)         // 64 point-pairs

#define TABN    2048                // 64 seg/octave x 32 octaves
#define EMIN    103                 // min biased exponent: t = 2^-24
#define IDX0    (EMIN * 64)         // 6592: (u>>17) at table start

typedef float v2f __attribute__((ext_vector_type(2)));

#define L2C 2.0813689810056077f     // (log2 e)^2

// Accumulators in .bss (zero-init at module load; validated R13). mfe_div
// re-zeros after reading -> invariant across graph replays. Self-healing for
// the ratio: k main-runs scale both sums by k, ratio unchanged.
__device__ float g_psw[NQ];
__device__ float g_pswf[NQ];

__global__ __launch_bounds__(THREADS) void mfe_main(
    const float* __restrict__ qp,     // [B,N,3]
    const float* __restrict__ sp,     // [B,M,3]
    const float* __restrict__ feats)  // [B,M,1]
{
    __shared__ float tabB[TABN];           // slope   : 8 KB
    __shared__ float tabC[TABN];           // intercept: 8 KB
    __shared__ float4 xy2[PAIRS];          // {x0, x1, y0, y1} : 1 KB
    __shared__ float4 zf2[PAIRS];          // {z0, z1, f0, f1} : 1 KB

    const int tid  = threadIdx.x;
    const int qg   = blockIdx.x;           // 0..QGROUPS-1
    const int s    = blockIdx.y;           // 0..SPLITS-1
    const int lane = tid & 63;
    const int w    = tid >> 6;
    const int qbase = qg * QPB + w * (QPT * 64) + lane;  // +k*64, k=0..3
    const int b     = qg / (N_DIM / QPB);  // batch (uniform per block)

    // Build the w(t) table: segment e covers t in [T(e), T(e+1)),
    // T(e) = as_float((e + IDX0) << 17). w ~= b*t + c on each segment.
    #pragma unroll
    for (int e = tid; e < TABN; e += THREADS) {
        const float t_lo = __uint_as_float((uint32_t)(e + IDX0)     << 17);
        const float t_hi = __uint_as_float((uint32_t)(e + IDX0 + 1) << 17);
        const float w_lo = __builtin_amdgcn_exp2f(-__builtin_amdgcn_sqrtf(t_lo));
        const float w_hi = __builtin_amdgcn_exp2f(-__builtin_amdgcn_sqrtf(t_hi));
        const float bb   = (w_hi - w_lo) / (t_hi - t_lo);  // exact denom
        tabB[e] = bb;
        tabC[e] = fmaf(-bb, t_lo, w_lo);   // c = w_lo - b*t_lo
    }

    // Stage: threads 0..63 each build one point-pair (z precomputed here).
    if (tid < PAIRS) {
        const int m0 = b * M_DIM + s * CHUNK + 2 * tid;
        const float x0 = sp[m0 * 3 + 0], y0 = sp[m0 * 3 + 1];
        const float x1 = sp[m0 * 3 + 3], y1 = sp[m0 * 3 + 4];
        const float f0 = feats[m0], f1 = feats[m0 + 1];
        xy2[tid] = make_float4(x0, x1, y0, y1);
        zf2[tid] = make_float4(L2C * fmaf(x0, x0, y0 * y0),
                               L2C * fmaf(x1, x1, y1 * y1), f0, f1);
    }

    // Per-query constants, splatted into pairs ONCE (movs outside the loop).
    // t = L2*d2 = ca*x + cb*y + (z + q2)
    v2f caS[QPT], cbS[QPT], q2S[QPT];
    #pragma unroll
    for (int k = 0; k < QPT; ++k) {
        const int q = qbase + k * 64;
        const float qx = qp[q * 3 + 0];
        const float qy = qp[q * 3 + 1];
        const float ca = -2.0f * L2C * qx;
        const float cb = -2.0f * L2C * qy;
        const float q2 = L2C * fmaf(qx, qx, qy * qy);
        caS[k] = (v2f){ ca, ca };
        cbS[k] = (v2f){ cb, cb };
        q2S[k] = (v2f){ q2, q2 };
    }

    v2f sw[QPT], swf[QPT];
    #pragma unroll
    for (int k = 0; k < QPT; ++k) { sw[k] = (v2f){0.f, 0.f}; swf[k] = (v2f){0.f, 0.f}; }

    __syncthreads();

    #pragma unroll 8
    for (int j = 0; j < PAIRS; ++j) {
        const float4 XY = xy2[j];          // wave-uniform addr -> broadcast
        const float4 ZF = zf2[j];
        const v2f X = { XY.x, XY.y };      // adjacent regs straight from b128
        const v2f Y = { XY.z, XY.w };
        const v2f Z = { ZF.x, ZF.y };
        const v2f F = { ZF.z, ZF.w };

        #pragma unroll
        for (int k = 0; k < QPT; ++k) {
            // t = ca*X + cb*Y + (Z + q2) — pure element-wise v2f
            const v2f t = __builtin_elementwise_fma(
                caS[k], X, __builtin_elementwise_fma(cbS[k], Y, Z + q2S[k]));
            // Table lookup: idx from |t|'s exponent+top-6-mantissa bits.
            const uint32_t u0 = __float_as_uint(t.x) & 0x7fffffffu;
            const uint32_t u1 = __float_as_uint(t.y) & 0x7fffffffu;
            int i0 = (int)(u0 >> 17) - IDX0;
            int i1 = (int)(u1 >> 17) - IDX0;
            i0 = i0 < 0 ? 0 : (i0 > TABN - 1 ? TABN - 1 : i0);
            i1 = i1 < 0 ? 0 : (i1 > TABN - 1 ? TABN - 1 : i1);
            v2f wv;
            wv.x = fmaf(tabB[i0], t.x, tabC[i0]);
            wv.y = fmaf(tabB[i1], t.y, tabC[i1]);
            sw[k]  = sw[k] + wv;
            swf[k] = __builtin_elementwise_fma(wv, F, swf[k]);
        }
    }

    #pragma unroll
    for (int k = 0; k < QPT; ++k) {
        const int q = qbase + k * 64;
        atomicAdd(&g_psw[q],  sw[k].x  + sw[k].y);   // fire-and-forget
        atomicAdd(&g_pswf[q], swf[k].x + swf[k].y);
    }
}

__global__ __launch_bounds__(256) void mfe_div(float* __restrict__ out)
{
    const int i = blockIdx.x * 256 + threadIdx.x;
    out[i] = g_pswf[i] / g_psw[i];
    g_psw[i]  = 0.0f;                      // restore zero-invariant
    g_pswf[i] = 0.0f;
}

extern "C" void kernel_launch(void* const* d_in, const int* in_sizes, int n_in,
                              void* d_out, int out_size, void* d_ws, size_t ws_size,
                              hipStream_t stream) {
    const float* qp    = (const float*)d_in[0];
    const float* sp    = (const float*)d_in[1];
    const float* feats = (const float*)d_in[2];
    float* out = (float*)d_out;
    (void)d_ws; (void)ws_size;             // accumulators live in .bss

    dim3 grid(QGROUPS, SPLITS);
    mfe_main<<<grid, THREADS, 0, stream>>>(qp, sp, feats);
    mfe_div<<<NQ / 256, 256, 0, stream>>>(out);
}

// Round 7
// 86.110 us; speedup vs baseline: 1.2924x; 1.2924x over previous
//
#include <hip/hip_runtime.h>

// out[b,n] = sum_m exp(-||qp[b,n,:2]-sp[b,m,:2]||) * f[b,m] / sum_m exp(-...)
// Shapes: qp [4,4096,3], sp [4,8192,3], feats [4,8192,1], out [4,4096,1] fp32.
//
// R16: RESTORE R13 (87.1us, best passing). Ledger of dead levers:
//  - memory paths (LDS / s_load / SW-pipeline): neutral x3 -> issue-bound
//  - VOP3P inline asm: 2 encodings, both numerically wrong -> dead
//  - LDS w(t) table: +24us, SQ_LDS_BANK_CONFLICT 1.9e7 (~half of kernel
//    cycles) -> gather conflicts, dead
//  - poly exp2: 9 ops/pt (trunc/cvt/ldexp have no pk forms) = 18cyc vs
//    16cyc trans -> dead on arithmetic
//  - NR-rsqrt: >=18cyc/pt scalar vs 16 -> dead unless compiler packs (it
//    doesn't, per 3 neutral rounds + cycle fit)
// Structural floor: 40us harness poison fill (256MiB @84% HBM peak, its own
// roofline) + ~38us main (27.3us trans floor + near-minimal VALU: 3 fma-class
// + 2 accum per point) + ~1.5us div + ~7us graph overhead = ~87us.
// Predict: pass @ absmax ~1.5e-5, 87.1 +/- 0.7us. Then declare roofline.

#define B_DIM   4
#define N_DIM   4096
#define M_DIM   8192
#define NQ      (B_DIM * N_DIM)     // 16384
#define THREADS 256
#define QPT     4                   // queries per thread
#define QPB     (THREADS * QPT)     // 1024 queries per block
#define QGROUPS (NQ / QPB)          // 16
#define SPLITS  64                  // M splits (blockIdx.y) -> 1024 blocks
#define CHUNK   (M_DIM / SPLITS)    // 128 scene points per block
#define PAIRS   (CHUNK / 2)         // 64 point-pairs

typedef float v2f __attribute__((ext_vector_type(2)));

#define L2C 2.0813689810056077f     // (log2 e)^2

// Accumulators in .bss (zero-init at module load; validated R13). mfe_div
// re-zeros after reading -> invariant across graph replays. Self-healing for
// the ratio: k main-runs scale both sums by k, ratio unchanged.
__device__ float g_psw[NQ];
__device__ float g_pswf[NQ];

__global__ __launch_bounds__(THREADS) void mfe_main(
    const float* __restrict__ qp,     // [B,N,3]
    const float* __restrict__ sp,     // [B,M,3]
    const float* __restrict__ feats)  // [B,M,1]
{
    __shared__ float4 xy2[PAIRS];          // {x0, x1, y0, y1} : 1 KB
    __shared__ float4 zf2[PAIRS];          // {z0, z1, f0, f1} : 1 KB

    const int tid  = threadIdx.x;
    const int qg   = blockIdx.x;           // 0..QGROUPS-1
    const int s    = blockIdx.y;           // 0..SPLITS-1
    const int lane = tid & 63;
    const int w    = tid >> 6;
    const int qbase = qg * QPB + w * (QPT * 64) + lane;  // +k*64, k=0..3
    const int b     = qg / (N_DIM / QPB);  // batch (uniform per block)

    // Stage: threads 0..63 each build one point-pair (z precomputed here).
    if (tid < PAIRS) {
        const int m0 = b * M_DIM + s * CHUNK + 2 * tid;
        const float x0 = sp[m0 * 3 + 0], y0 = sp[m0 * 3 + 1];
        const float x1 = sp[m0 * 3 + 3], y1 = sp[m0 * 3 + 4];
        const float f0 = feats[m0], f1 = feats[m0 + 1];
        xy2[tid] = make_float4(x0, x1, y0, y1);
        zf2[tid] = make_float4(L2C * fmaf(x0, x0, y0 * y0),
                               L2C * fmaf(x1, x1, y1 * y1), f0, f1);
    }

    // Per-query constants, splatted into pairs ONCE (movs outside the loop).
    // t = L2*d2 = ca*x + cb*y + (z + q2)
    v2f caS[QPT], cbS[QPT], q2S[QPT];
    #pragma unroll
    for (int k = 0; k < QPT; ++k) {
        const int q = qbase + k * 64;
        const float qx = qp[q * 3 + 0];
        const float qy = qp[q * 3 + 1];
        const float ca = -2.0f * L2C * qx;
        const float cb = -2.0f * L2C * qy;
        const float q2 = L2C * fmaf(qx, qx, qy * qy);
        caS[k] = (v2f){ ca, ca };
        cbS[k] = (v2f){ cb, cb };
        q2S[k] = (v2f){ q2, q2 };
    }

    v2f sw[QPT], swf[QPT];
    #pragma unroll
    for (int k = 0; k < QPT; ++k) { sw[k] = (v2f){0.f, 0.f}; swf[k] = (v2f){0.f, 0.f}; }

    __syncthreads();

    #pragma unroll 8
    for (int j = 0; j < PAIRS; ++j) {
        const float4 XY = xy2[j];          // wave-uniform addr -> broadcast
        const float4 ZF = zf2[j];
        const v2f X = { XY.x, XY.y };      // adjacent regs straight from b128
        const v2f Y = { XY.z, XY.w };
        const v2f Z = { ZF.x, ZF.y };
        const v2f F = { ZF.z, ZF.w };

        #pragma unroll
        for (int k = 0; k < QPT; ++k) {
            // t = ca*X + cb*Y + (Z + q2) — pure element-wise v2f
            const v2f t = __builtin_elementwise_fma(
                caS[k], X, __builtin_elementwise_fma(cbS[k], Y, Z + q2S[k]));
            v2f wv;                        // abs/neg fold into src modifiers
            wv.x = __builtin_amdgcn_exp2f(-__builtin_amdgcn_sqrtf(__builtin_fabsf(t.x)));
            wv.y = __builtin_amdgcn_exp2f(-__builtin_amdgcn_sqrtf(__builtin_fabsf(t.y)));
            sw[k]  = sw[k] + wv;
            swf[k] = __builtin_elementwise_fma(wv, F, swf[k]);
        }
    }

    #pragma unroll
    for (int k = 0; k < QPT; ++k) {
        const int q = qbase + k * 64;
        atomicAdd(&g_psw[q],  sw[k].x  + sw[k].y);   // fire-and-forget
        atomicAdd(&g_pswf[q], swf[k].x + swf[k].y);
    }
}

__global__ __launch_bounds__(256) void mfe_div(float* __restrict__ out)
{
    const int i = blockIdx.x * 256 + threadIdx.x;
    out[i] = g_pswf[i] / g_psw[i];
    g_psw[i]  = 0.0f;                      // restore zero-invariant
    g_pswf[i] = 0.0f;
}

extern "C" void kernel_launch(void* const* d_in, const int* in_sizes, int n_in,
                              void* d_out, int out_size, void* d_ws, size_t ws_size,
                              hipStream_t stream) {
    const float* qp    = (const float*)d_in[0];
    const float* sp    = (const float*)d_in[1];
    const float* feats = (const float*)d_in[2];
    float* out = (float*)d_out;
    (void)d_ws; (void)ws_size;             // accumulators live in .bss

    dim3 grid(QGROUPS, SPLITS);
    mfe_main<<<grid, THREADS, 0, stream>>>(qp, sp, feats);
    mfe_div<<<NQ / 256, 256, 0, stream>>>(out);
}